// Round 1
// baseline (3623.768 us; speedup 1.0000x reference)
//
#include <hip/hip_runtime.h>
#include <hip/hip_bf16.h>
#include <math.h>

typedef __bf16 bf16;
typedef bf16  bf16x8 __attribute__((ext_vector_type(8)));
typedef float f32x4  __attribute__((ext_vector_type(4)));

#define DM    4096
#define KEXP  8
#define DHID  2048
#define DPROJ 512
#define NTOK  4096
#define D2    8192
#define FTOT  16384

// ---------------------------------------------------------------------------
// async global->LDS, 16B per lane (m97 recipe)
// ---------------------------------------------------------------------------
__device__ __forceinline__ void gload_lds16(const void* g, void* l) {
  __builtin_amdgcn_global_load_lds((__attribute__((address_space(1))) unsigned int*)g,
                                   (__attribute__((address_space(3))) unsigned int*)l,
                                   16, 0, 0);
}

// ---------------------------------------------------------------------------
// fp32 -> bf16 copy building cond = [anchor | mask], [NTOK, D2]
// each thread converts 8 contiguous elements (never straddles the 4096 seam)
// ---------------------------------------------------------------------------
__global__ void cvt_cond(const float* __restrict__ ha, const float* __restrict__ hm,
                         bf16* __restrict__ cond) {
  size_t t = (size_t)blockIdx.x * 256 + threadIdx.x;
  size_t e = t * 8;
  int n = (int)(e >> 13);
  int c = (int)(e & 8191);
  const float* src = (c < DM) ? (ha + ((size_t)n << 12) + c)
                              : (hm + ((size_t)n << 12) + (c - DM));
  float4 v0 = ((const float4*)src)[0];
  float4 v1 = ((const float4*)src)[1];
  union { bf16 h[8]; uint4 u; } pk;
  pk.h[0] = (bf16)v0.x; pk.h[1] = (bf16)v0.y; pk.h[2] = (bf16)v0.z; pk.h[3] = (bf16)v0.w;
  pk.h[4] = (bf16)v1.x; pk.h[5] = (bf16)v1.y; pk.h[6] = (bf16)v1.z; pk.h[7] = (bf16)v1.w;
  *(uint4*)(cond + e) = pk.u;
}

// ---------------------------------------------------------------------------
// generic transpose + fp32->bf16: in fp32 [R][C] row-major (+z*in_zs),
// out bf16: out[c*ostride + r] (+z*out_zs).  64x64 LDS tiles.
// ---------------------------------------------------------------------------
__global__ void tcvt(const float* __restrict__ in, bf16* __restrict__ out,
                     int R, int C, long in_zs, long out_zs, int ostride) {
  __shared__ float tile[64][65];
  const int bx = blockIdx.x, by = blockIdx.y, bz = blockIdx.z;
  in  += (size_t)bz * in_zs;
  out += (size_t)bz * out_zs;
  const int t  = threadIdx.x;
  const int r  = t >> 2;
  const int c4 = (t & 3) * 16;
  const float* src = in + (size_t)(by * 64 + r) * C + bx * 64 + c4;
#pragma unroll
  for (int i = 0; i < 4; i++) {
    float4 v = ((const float4*)src)[i];
    tile[r][c4 + i * 4 + 0] = v.x;
    tile[r][c4 + i * 4 + 1] = v.y;
    tile[r][c4 + i * 4 + 2] = v.z;
    tile[r][c4 + i * 4 + 3] = v.w;
  }
  __syncthreads();
  const int oc  = t >> 2;        // out row (= in col within tile)
  const int or4 = (t & 3) * 16;  // out col base (= in row within tile)
  union { bf16 h[16]; uint4 u[2]; } pk;
#pragma unroll
  for (int i = 0; i < 16; i++) pk.h[i] = (bf16)tile[or4 + i][oc];
  bf16* dst = out + (size_t)(bx * 64 + oc) * ostride + by * 64 + or4;
  ((uint4*)dst)[0] = pk.u[0];
  ((uint4*)dst)[1] = pk.u[1];
}

// ---------------------------------------------------------------------------
// routing: weights[n, 0:8] = softmax(h_mask[n,:] @ Wr + br)   (pure fp32)
// one block (256 thr) per row
// ---------------------------------------------------------------------------
__global__ void routing(const float* __restrict__ hm, const float* __restrict__ Wr,
                        const float* __restrict__ br, float* __restrict__ wout) {
  const int n = blockIdx.x, t = threadIdx.x;
  float acc[8] = {0.f, 0.f, 0.f, 0.f, 0.f, 0.f, 0.f, 0.f};
  const float* row = hm + (size_t)n * DM;
  for (int d = t; d < DM; d += 256) {
    float x = row[d];
    const float4* wr = (const float4*)(Wr + (size_t)d * 8);
    float4 a = wr[0], b = wr[1];
    acc[0] += x * a.x; acc[1] += x * a.y; acc[2] += x * a.z; acc[3] += x * a.w;
    acc[4] += x * b.x; acc[5] += x * b.y; acc[6] += x * b.z; acc[7] += x * b.w;
  }
#pragma unroll
  for (int off = 32; off > 0; off >>= 1)
#pragma unroll
    for (int j = 0; j < 8; j++) acc[j] += __shfl_down(acc[j], off);
  __shared__ float red[4][8];
  const int w = t >> 6, lane = t & 63;
  if (lane == 0)
#pragma unroll
    for (int j = 0; j < 8; j++) red[w][j] = acc[j];
  __syncthreads();
  if (t == 0) {
    float lg[8];
#pragma unroll
    for (int j = 0; j < 8; j++)
      lg[j] = red[0][j] + red[1][j] + red[2][j] + red[3][j] + br[j];
    float mx = lg[0];
#pragma unroll
    for (int j = 1; j < 8; j++) mx = fmaxf(mx, lg[j]);
    float s = 0.f;
#pragma unroll
    for (int j = 0; j < 8; j++) { lg[j] = expf(lg[j] - mx); s += lg[j]; }
    float inv = 1.f / s;
#pragma unroll
    for (int j = 0; j < 8; j++) wout[(size_t)n * 8 + j] = lg[j] * inv;
  }
}

// ---------------------------------------------------------------------------
// relevance: rel[n] = sigmoid( dot(Q[n], K[n]) / sqrt(DPROJ) ); 1 wave per row
// ---------------------------------------------------------------------------
__global__ void relk(const float* __restrict__ Q, const float* __restrict__ Kv,
                     float* __restrict__ rel) {
  const int n = blockIdx.x, lane = threadIdx.x;
  const float4* q = (const float4*)(Q + (size_t)n * DPROJ);
  const float4* k = (const float4*)(Kv + (size_t)n * DPROJ);
  float s = 0.f;
  float4 a = q[lane],      b = k[lane];
  s += a.x * b.x + a.y * b.y + a.z * b.z + a.w * b.w;
  a = q[lane + 64]; b = k[lane + 64];
  s += a.x * b.x + a.y * b.y + a.z * b.z + a.w * b.w;
#pragma unroll
  for (int off = 32; off > 0; off >>= 1) s += __shfl_down(s, off);
  if (lane == 0) rel[n] = 1.f / (1.f + expf(-s * 0.04419417382415922f));
}

// ---------------------------------------------------------------------------
// m97-style bf16 GEMM, C = A @ BT^T.  A:[M][lda] bf16, BT:[N][ldb] bf16.
// 128x128 tile, BK=32, 256 thr (4 waves, 2x2), mfma_f32_16x16x32_bf16.
// EPI 0: C fp32 = acc + bias[col]                         (q/k projections)
// EPI 1: C bf16 = gelu(acc + bias[col]) * wts[n, col>>11] (GEMM1 -> hidp)
// EPI 2: C fp32 = (acc + sum_k wts[n,k]*b2[k,col]) * rel[n]  (GEMM2 -> out)
// ---------------------------------------------------------------------------
template <int EPI>
__global__ __launch_bounds__(256)
void gemm_bt(const bf16* __restrict__ A, int lda,
             const bf16* __restrict__ BT, int ldb,
             void* __restrict__ Cout, int ldc, int kdim,
             const float* __restrict__ bias,
             const float* __restrict__ wts,
             const float* __restrict__ b2,
             const float* __restrict__ rel) {
  __shared__ ushort sA[128 * 32];
  __shared__ ushort sB[128 * 32];
  const int tid  = threadIdx.x;
  const int wave = tid >> 6, lane = tid & 63;
  const int m0 = blockIdx.x * 128;   // x = M tiles (fast dim) for B-stripe L2 reuse
  const int n0 = blockIdx.y * 128;
  const int wy = wave >> 1, wx = wave & 1;
  const int fr = lane & 15, fq = lane >> 4;

  f32x4 acc[4][4];
  const f32x4 zero = {0.f, 0.f, 0.f, 0.f};
#pragma unroll
  for (int i = 0; i < 4; i++)
#pragma unroll
    for (int j = 0; j < 4; j++) acc[i][j] = zero;

  // staging: 8 KiB per matrix = 8 chunks of 1 KiB; wave w stages chunks 2w, 2w+1
  const int idx0 = (wave * 2) * 64 + lane;
  const int idx1 = idx0 + 64;
  const int ar0 = idx0 >> 2, ac0 = (idx0 & 3) * 8;
  const int ar1 = idx1 >> 2, ac1 = (idx1 & 3) * 8;
  const bf16* Ab = A + (size_t)m0 * lda;
  const bf16* Bb = BT + (size_t)n0 * ldb;
  const bf16* ga0 = Ab + (size_t)ar0 * lda + ac0;
  const bf16* ga1 = Ab + (size_t)ar1 * lda + ac1;
  const bf16* gb0 = Bb + (size_t)ar0 * ldb + ac0;
  const bf16* gb1 = Bb + (size_t)ar1 * ldb + ac1;
  ushort* la0 = sA + idx0 * 8;
  ushort* la1 = sA + idx1 * 8;
  ushort* lb0 = sB + idx0 * 8;
  ushort* lb1 = sB + idx1 * 8;

  for (int kt = 0; kt < kdim; kt += 32) {
    gload_lds16(ga0 + kt, la0);
    gload_lds16(ga1 + kt, la1);
    gload_lds16(gb0 + kt, lb0);
    gload_lds16(gb1 + kt, lb1);
    __syncthreads();                    // drains vmcnt, loads visible
    bf16x8 aF[4], bF[4];
#pragma unroll
    for (int mi = 0; mi < 4; mi++)
      aF[mi] = *(const bf16x8*)&sA[(wy * 64 + mi * 16 + fr) * 32 + fq * 8];
#pragma unroll
    for (int ni = 0; ni < 4; ni++)
      bF[ni] = *(const bf16x8*)&sB[(wx * 64 + ni * 16 + fr) * 32 + fq * 8];
#pragma unroll
    for (int mi = 0; mi < 4; mi++)
#pragma unroll
      for (int ni = 0; ni < 4; ni++)
        acc[mi][ni] = __builtin_amdgcn_mfma_f32_16x16x32_bf16(aF[mi], bF[ni], acc[mi][ni], 0, 0, 0);
    __syncthreads();                    // all waves done reading before restage
  }

  if (EPI == 0) {
    float* C = (float*)Cout;
#pragma unroll
    for (int mi = 0; mi < 4; mi++)
#pragma unroll
      for (int r = 0; r < 4; r++) {
        const int n = m0 + wy * 64 + mi * 16 + fq * 4 + r;
#pragma unroll
        for (int ni = 0; ni < 4; ni++) {
          const int col = n0 + wx * 64 + ni * 16 + fr;
          C[(size_t)n * ldc + col] = acc[mi][ni][r] + bias[col];
        }
      }
  } else if (EPI == 1) {
    bf16* C = (bf16*)Cout;
#pragma unroll
    for (int mi = 0; mi < 4; mi++)
#pragma unroll
      for (int r = 0; r < 4; r++) {
        const int n = m0 + wy * 64 + mi * 16 + fq * 4 + r;
        const float* wrow = wts + (size_t)n * 8;
#pragma unroll
        for (int ni = 0; ni < 4; ni++) {
          const int col = n0 + wx * 64 + ni * 16 + fr;
          float x = acc[mi][ni][r] + bias[col];
          float g = 0.5f * x * (1.f + erff(x * 0.7071067811865475f));
          C[(size_t)n * ldc + col] = (bf16)(g * wrow[col >> 11]);
        }
      }
  } else {
    float* C = (float*)Cout;
    float b2c[4][8];
#pragma unroll
    for (int ni = 0; ni < 4; ni++) {
      const int col = n0 + wx * 64 + ni * 16 + fr;
#pragma unroll
      for (int k = 0; k < 8; k++) b2c[ni][k] = b2[(size_t)k * DM + col];
    }
#pragma unroll
    for (int mi = 0; mi < 4; mi++)
#pragma unroll
      for (int r = 0; r < 4; r++) {
        const int n = m0 + wy * 64 + mi * 16 + fq * 4 + r;
        const float4* wv = (const float4*)(wts + (size_t)n * 8);
        const float4 w0 = wv[0], w1 = wv[1];
        const float rl = rel[n];
#pragma unroll
        for (int ni = 0; ni < 4; ni++) {
          const int col = n0 + wx * 64 + ni * 16 + fr;
          float bb = w0.x * b2c[ni][0] + w0.y * b2c[ni][1] + w0.z * b2c[ni][2] + w0.w * b2c[ni][3]
                   + w1.x * b2c[ni][4] + w1.y * b2c[ni][5] + w1.z * b2c[ni][6] + w1.w * b2c[ni][7];
          C[(size_t)n * ldc + col] = (acc[mi][ni][r] + bb) * rl;
        }
      }
  }
}

// ---------------------------------------------------------------------------
extern "C" void kernel_launch(void* const* d_in, const int* in_sizes, int n_in,
                              void* d_out, int out_size, void* d_ws, size_t ws_size,
                              hipStream_t stream) {
  const float* h_anchor = (const float*)d_in[0];
  const float* h_mask   = (const float*)d_in[1];
  const float* Wr = (const float*)d_in[2];
  const float* br = (const float*)d_in[3];
  const float* W1 = (const float*)d_in[4];
  const float* b1 = (const float*)d_in[5];
  const float* W2 = (const float*)d_in[6];
  const float* b2 = (const float*)d_in[7];
  const float* Wq = (const float*)d_in[8];
  const float* bq = (const float*)d_in[9];
  const float* Wk = (const float*)d_in[10];
  const float* bk = (const float*)d_in[11];
  float* out = (float*)d_out;

  char* ws = (char*)d_ws;
  size_t off = 0;
  bf16* cond = (bf16*)(ws + off); off += (size_t)NTOK * D2 * 2;     // 64 MiB
  bf16* W1T  = (bf16*)(ws + off); off += (size_t)FTOT * D2 * 2;     // 256 MiB  [f_glob][d]
  bf16* W2T  = (bf16*)(ws + off); off += (size_t)DM * FTOT * 2;     // 128 MiB  [d][k*2048+f]
  bf16* hidp = (bf16*)(ws + off); off += (size_t)NTOK * FTOT * 2;   // 128 MiB
  bf16* WqT  = (bf16*)(ws + off); off += (size_t)DPROJ * DM * 2;    // 4 MiB
  bf16* WkT  = (bf16*)(ws + off); off += (size_t)DPROJ * DM * 2;    // 4 MiB
  float* Q   = (float*)(ws + off); off += (size_t)NTOK * DPROJ * 4; // 8 MiB
  float* Kv  = (float*)(ws + off); off += (size_t)NTOK * DPROJ * 4; // 8 MiB
  float* wts = (float*)(ws + off); off += (size_t)NTOK * KEXP * 4;
  float* rel = (float*)(ws + off); off += (size_t)NTOK * 4;
  if (ws_size < off) return;  // workspace too small: fail cleanly (signals pivot)

  // 1) conversions / transposes (pure HBM-bound)
  cvt_cond<<<(NTOK * D2 / 8) / 256, 256, 0, stream>>>(h_anchor, h_mask, cond);
  // W1 [k][d=8192][f=2048] -> W1T [k*2048+f][d]
  tcvt<<<dim3(DHID / 64, D2 / 64, KEXP), 256, 0, stream>>>(
      W1, W1T, D2, DHID, (long)D2 * DHID, (long)DHID * D2, D2);
  // W2 [k][f=2048][d=4096] -> W2T [d][k*2048+f]  (row stride FTOT, z offset 2048)
  tcvt<<<dim3(DM / 64, DHID / 64, KEXP), 256, 0, stream>>>(
      W2, W2T, DHID, DM, (long)DHID * DM, (long)DHID, FTOT);
  // Wq/Wk [d=4096][p=512] -> [p][d]
  tcvt<<<dim3(DPROJ / 64, DM / 64, 1), 256, 0, stream>>>(Wq, WqT, DM, DPROJ, 0, 0, DM);
  tcvt<<<dim3(DPROJ / 64, DM / 64, 1), 256, 0, stream>>>(Wk, WkT, DM, DPROJ, 0, 0, DM);

  // 2) routing weights (fp32 exact)
  routing<<<NTOK, 256, 0, stream>>>(h_mask, Wr, br, wts);

  // 3) relevance gate: Q = mask@Wq, K = anchor@Wk, rel = sigmoid(q.k/sqrt(P))
  gemm_bt<0><<<dim3(NTOK / 128, DPROJ / 128), 256, 0, stream>>>(
      cond + DM, D2, WqT, DM, Q, DPROJ, DM, bq, nullptr, nullptr, nullptr);
  gemm_bt<0><<<dim3(NTOK / 128, DPROJ / 128), 256, 0, stream>>>(
      cond, D2, WkT, DM, Kv, DPROJ, DM, bk, nullptr, nullptr, nullptr);
  relk<<<NTOK, 64, 0, stream>>>(Q, Kv, rel);

  // 4) GEMM1: hidp = gelu(cond @ W1 + b1) * w   [4096 x 16384], K=8192
  gemm_bt<1><<<dim3(NTOK / 128, FTOT / 128), 256, 0, stream>>>(
      cond, D2, W1T, D2, hidp, FTOT, D2, b1, wts, nullptr, nullptr);

  // 5) GEMM2: out = (hidp @ W2cat + sum_k w*b2) * rel   [4096 x 4096], K=16384
  gemm_bt<2><<<dim3(NTOK / 128, DM / 128), 256, 0, stream>>>(
      hidp, FTOT, W2T, FTOT, out, DM, FTOT, nullptr, wts, b2, rel);
}